// Round 6
// baseline (875.328 us; speedup 1.0000x reference)
//
#include <hip/hip_runtime.h>

#define SEQ 1024
#define NH  16

typedef __attribute__((ext_vector_type(8))) short short8;
typedef __attribute__((ext_vector_type(4))) float floatx4;
typedef __attribute__((ext_vector_type(4))) unsigned short ushortx4;

// async global->LDS, 16B per lane; LDS dest = wave-uniform base + lane*16
#define GLDS16(gp, lp) __builtin_amdgcn_global_load_lds( \
    (const __attribute__((address_space(1))) void*)(gp), \
    (__attribute__((address_space(3))) void*)(lp), 16, 0, 0)

__device__ __forceinline__ unsigned short f2b(float f) {   // fp32 -> bf16 RNE
    union { float f; unsigned u; } v; v.f = f;
    unsigned r = (v.u + 0x7fffu + ((v.u >> 16) & 1u)) >> 16;
    return (unsigned short)r;
}
__device__ __forceinline__ float b2f(unsigned short h) {
    union { unsigned u; float f; } v; v.u = ((unsigned)h) << 16;
    return v.f;
}

// swizzled addr helper (element offsets in a 64-wide bf16 tile: 8 chunks of 16B/row)
#define TADDR(base, row, ch) ((base) + ((row) << 6) + ((((ch) ^ ((row) & 7))) << 3))

// ---------------- k0: fp32 -> bf16 casts ----------------
__global__ void cast_kernel(const float* __restrict__ hs, const float* __restrict__ W,
                            const float* __restrict__ E,
                            unsigned short* __restrict__ hsb,
                            unsigned short* __restrict__ Wb,
                            unsigned short* __restrict__ Eb)
{
    const int QH = 1048576, QW = 786432, QE = 32752;   // quads
    const int NT = QH + QW + QE;
    for (int q = blockIdx.x * 256 + threadIdx.x; q < NT; q += gridDim.x * 256) {
        const float* src; unsigned short* dst; int off;
        if (q < QH)           { src = hs; dst = hsb; off = q; }
        else if (q < QH + QW) { src = W;  dst = Wb;  off = q - QH; }
        else                  { src = E;  dst = Eb;  off = q - QH - QW; }
        const float4 v = *(const float4*)(src + (size_t)off * 4);
        ushortx4 o; o[0] = f2b(v.x); o[1] = f2b(v.y); o[2] = f2b(v.z); o[3] = f2b(v.w);
        *(ushortx4*)(dst + (size_t)off * 4) = o;
    }
}

// ---------------- k1: QKV projection, bf16 MFMA, NT layout ----------------
__global__ __launch_bounds__(256, 3) void qkv_gemm(
    const unsigned short* __restrict__ Ab, const unsigned short* __restrict__ Bb,
    const float* __restrict__ bias,
    unsigned short* __restrict__ Qb, unsigned short* __restrict__ Kb,
    unsigned short* __restrict__ Vt)
{
    __shared__ unsigned short sm[8192];          // A [0,4096), B [4096,8192) elems
    const int t = threadIdx.x, w = t >> 6;
    const int ln = t & 15, g = (t >> 4) & 3;
    const int wm = w >> 1, wn = w & 1;
    const int m0 = blockIdx.y << 7, o0 = blockIdx.x << 7;

    floatx4 acc[4][4];
#pragma unroll
    for (int i = 0; i < 4; ++i)
#pragma unroll
        for (int j = 0; j < 4; ++j) acc[i][j] = (floatx4){0.f, 0.f, 0.f, 0.f};

    auto stage = [&](int kb) {
#pragma unroll
        for (int p = 0; p < 2; ++p) {
            const int idx = (p << 8) + t;
            const int row = idx >> 2;
            const int c = (idx & 3) ^ ((row ^ (row >> 2)) & 3);
            GLDS16(Ab + (size_t)(m0 + row) * 1024 + kb + (c << 3),
                   (char*)sm + (p << 12) + (w << 10));
            GLDS16(Bb + (size_t)(o0 + row) * 1024 + kb + (c << 3),
                   (char*)sm + 8192 + (p << 12) + (w << 10));
        }
    };

    stage(0);
    for (int kb = 0;;) {
        __syncthreads();
        short8 af[4], bf_[4];
#pragma unroll
        for (int i = 0; i < 4; ++i) {
            const int r = (wm << 6) + (i << 4) + ln;
            af[i] = *(const short8*)&sm[(r << 5) + ((g ^ ((r ^ (r >> 2)) & 3)) << 3)];
        }
#pragma unroll
        for (int j = 0; j < 4; ++j) {
            const int r = (wn << 6) + (j << 4) + ln;
            bf_[j] = *(const short8*)&sm[4096 + (r << 5) + ((g ^ ((r ^ (r >> 2)) & 3)) << 3)];
        }
#pragma unroll
        for (int i = 0; i < 4; ++i)
#pragma unroll
            for (int j = 0; j < 4; ++j)
                acc[i][j] = __builtin_amdgcn_mfma_f32_16x16x32_bf16(af[i], bf_[j], acc[i][j], 0, 0, 0);
        kb += 32;
        if (kb >= 1024) break;
        __syncthreads();
        stage(kb);
    }

    const int which = o0 >> 10;     // 0=Q 1=K 2=V (block-uniform)
    float bj[4];
#pragma unroll
    for (int j = 0; j < 4; ++j) bj[j] = bias[o0 + (wn << 6) + (j << 4) + ln];

    if (which == 2) {               // V transposed: Vt[bh][d][s]
#pragma unroll
        for (int i = 0; i < 4; ++i) {
            const int m = m0 + (wm << 6) + (i << 4) + (g << 2);
            const int b = m >> 10, s = m & 1023;
#pragma unroll
            for (int j = 0; j < 4; ++j) {
                const int o = o0 + (wn << 6) + (j << 4) + ln;
                const int d = o & 63, hh = (o >> 6) & 15;
                ushortx4 pk;
#pragma unroll
                for (int q = 0; q < 4; ++q) pk[q] = f2b(acc[i][j][q] + bj[j]);
                *(ushortx4*)(Vt + (((size_t)((b << 4) + hh)) << 16) + (d << 10) + s) = pk;
            }
        }
    } else {
        unsigned short* dst = which ? Kb : Qb;
        const float sc = which ? 1.0f : 0.125f;   // fold 1/sqrt(64) into Q
#pragma unroll
        for (int i = 0; i < 4; ++i)
#pragma unroll
            for (int q = 0; q < 4; ++q) {
                const int m = m0 + (wm << 6) + (i << 4) + (g << 2) + q;
                const int b = m >> 10, s = m & 1023;
#pragma unroll
                for (int j = 0; j < 4; ++j) {
                    const int o = o0 + (wn << 6) + (j << 4) + ln;
                    const int d = o & 63, hh = (o >> 6) & 15;
                    dst[(((size_t)((b << 4) + hh)) << 16) + (s << 6) + d] =
                        f2b((acc[i][j][q] + bj[j]) * sc);
                }
            }
    }
}

// ---------------- k2: flash attention, 40 KiB LDS -> 4 blocks/CU ----------------
// Round-2 skeleton (4 barriers/tile, full K/E restage, V over dead E), plus:
//  * U/W terms accumulate into ONE 64x64 f32 LDS buffer via ds_add_f32.
//    Out-of-band shear cells are exec-predicated off (no guard rows).
//    Reader zero-restores its own cells after the read (bijective (r,l) map).
//  * P tile overlays the K region (K dead after frag reads; P fully rewritten).
//  * mask loads hoisted to tile top; s_setprio(1) around MFMA clusters.
// LDS elems (u16): K[0,4096)+P overlay | E[4096,12288) (V overlays [4096,8192) at C)
//                  UWf32 [12288,20480) = 4096 f32, cell(r,l) = r*64 + ((l>>2 ^ (r&15))<<2) + (l&3)
// total 20480 elems = 40960 B exactly -> 4 blocks/CU (grid 1024 = 256x4, zero tail)
__global__ __launch_bounds__(256, 4) void attn_mfma(
    const unsigned short* __restrict__ Qb, const unsigned short* __restrict__ Kb,
    const unsigned short* __restrict__ Vt, const unsigned short* __restrict__ Eb,
    const float* __restrict__ mask, float* __restrict__ outp)
{
    __shared__ __align__(16) unsigned short sm[20480];
    float* uwf = (float*)&sm[12288];             // 4096 f32 accumulator
    const int t = threadIdx.x, w = t >> 6;
    const int wu = __builtin_amdgcn_readfirstlane(w);   // wave-uniform in SGPR
    const int ln = t & 15, g = (t >> 4) & 3;
    const int bid = blockIdx.x;
    const int swz = ((bid & 7) << 7) | (bid >> 3);      // XCD-bijective (1024%8==0)
    const int bh = swz >> 4;
    const int l0 = (swz & 15) << 6;
    const int b = bh >> 4, h = bh & 15;
    const size_t hb = (size_t)bh << 16;
    const int x0 = (w << 4) + (g << 2);          // thread's base l-row
    const int cb = x0 >> 2;                      // col-block for UW swizzle

    // Q fragments direct from global (pre-scaled; L2-hot)
    const int qr = (w << 4) + ln;
    const short8 qa0 = *(const short8*)(Qb + hb + ((size_t)(l0 + qr) << 6) + (g << 3));
    const short8 qa1 = *(const short8*)(Qb + hb + ((size_t)(l0 + qr) << 6) + 32 + (g << 3));

    // prologue: zero this thread's 16 UW cells (barrier A orders vs first adds)
#pragma unroll
    for (int j = 0; j < 4; ++j) {
        const int rr = (j << 4) + ln;
        *(floatx4*)&uwf[(rr << 6) + ((cb ^ (rr & 15)) << 2)] = (floatx4){0.f, 0.f, 0.f, 0.f};
    }

    floatx4 O[4];
    float mr[4], lr[4];
#pragma unroll
    for (int dt = 0; dt < 4; ++dt) O[dt] = (floatx4){0.f, 0.f, 0.f, 0.f};
#pragma unroll
    for (int q = 0; q < 4; ++q) { mr[q] = -1e30f; lr[q] = 0.f; }

    for (int r0 = 0; r0 < SEQ; r0 += 64) {
        // hoist mask loads (consumed ~1.5k cyc later in scores)
        float mk4[4];
#pragma unroll
        for (int j = 0; j < 4; ++j) mk4[j] = mask[(b << 10) + r0 + (j << 4) + ln];

        __syncthreads();                         // A: prev PV/P reads done; zeros visible
#pragma unroll
        for (int p = 0; p < 2; ++p) {            // stage K at elem 0
            const int idx = (p << 8) + t;
            const int row = idx >> 3;
            const int c = (idx & 7) ^ (row & 7);
            GLDS16(Kb + hb + ((size_t)(r0 + row) << 6) + (c << 3),
                   (char*)sm + (p << 12) + (w << 10));
        }
        const int j0 = l0 - r0 + 960;            // E band start, in [0,1920]
#pragma unroll
        for (int p = 0; p < 4; ++p) {            // stage E (128 rows) at elem 4096
            const int idx = (p << 8) + t;
            const int row = idx >> 3;
            const int c = (idx & 7) ^ (row & 7);
            GLDS16(Eb + ((size_t)(j0 + row) << 6) + (c << 3),
                   (char*)sm + 8192 + (p << 12) + (w << 10));
        }
        __syncthreads();                         // B: staging visible

        short8 kf[4][2];
#pragma unroll
        for (int j = 0; j < 4; ++j) {
            const int kr = (j << 4) + ln;
            kf[j][0] = *(const short8*)&sm[TADDR(0, kr, g)];
            kf[j][1] = *(const short8*)&sm[TADDR(0, kr, 4 + g)];
        }
        const int wr = (w << 4) + ln;            // W A-fragment (this wave's K rows)
        const short8 ka0 = *(const short8*)&sm[TADDR(0, wr, g)];
        const short8 ka1 = *(const short8*)&sm[TADDR(0, wr, 4 + g)];

        __builtin_amdgcn_s_setprio(1);
        floatx4 S[4];
#pragma unroll
        for (int j = 0; j < 4; ++j) {
            floatx4 z = (floatx4){0.f, 0.f, 0.f, 0.f};
            z = __builtin_amdgcn_mfma_f32_16x16x32_bf16(qa0, kf[j][0], z, 0, 0, 0);
            S[j] = __builtin_amdgcn_mfma_f32_16x16x32_bf16(qa1, kf[j][1], z, 0, 0, 0);
        }
        // band GEMMs, pruned per wave; predicated ds_add_f32 into combined buffer
#pragma unroll
        for (int dt = 0; dt < 8; ++dt) {
            const bool doU = (dt >= wu) && (dt <= wu + 4);
            const bool doW = (dt >= 3 - wu) && (dt <= 7 - wu);
            if (!doU && !doW) continue;
            const int er = (dt << 4) + ln;
            const short8 e0 = *(const short8*)&sm[TADDR(4096, er, g)];
            const short8 e1 = *(const short8*)&sm[TADDR(4096, er, 4 + g)];
            if (doU) {
                floatx4 z = (floatx4){0.f, 0.f, 0.f, 0.f};
                z = __builtin_amdgcn_mfma_f32_16x16x32_bf16(qa0, e0, z, 0, 0, 0);
                const floatx4 U = __builtin_amdgcn_mfma_f32_16x16x32_bf16(qa1, e1, z, 0, 0, 0);
#pragma unroll
                for (int q = 0; q < 4; ++q) {
                    const int ru = x0 + q - (dt << 4) - ln + 63;  // cell (ru, x0+q)
                    if ((unsigned)ru < 64u)
                        atomicAdd(&uwf[(ru << 6) + (((cb ^ (ru & 15)) << 2) | q)], U[q]);
                }
            }
            if (doW) {
                floatx4 z2 = (floatx4){0.f, 0.f, 0.f, 0.f};
                z2 = __builtin_amdgcn_mfma_f32_16x16x32_bf16(ka0, e0, z2, 0, 0, 0);
                const floatx4 Wv = __builtin_amdgcn_mfma_f32_16x16x32_bf16(ka1, e1, z2, 0, 0, 0);
#pragma unroll
                for (int q = 0; q < 4; ++q) {
                    const int lw = x0 + q + (dt << 4) + ln - 63;  // cell (x0+q, lw)
                    if ((unsigned)lw < 64u)
                        atomicAdd(&uwf[((x0 + q) << 6) +
                                       ((((lw >> 2) ^ ((x0 + q) & 15)) << 2) | (lw & 3))],
                                  Wv[q] * 0.125f);
                }
            }
        }
        __builtin_amdgcn_s_setprio(0);
        __syncthreads();                         // C: UW sums complete; E dead

#pragma unroll
        for (int p = 0; p < 2; ++p) {            // stage V (transposed) over dead E
            const int idx = (p << 8) + t;
            const int row = idx >> 3;            // = d
            const int c = (idx & 7) ^ (row & 7);
            GLDS16(Vt + hb + ((size_t)row << 10) + r0 + (c << 3),
                   (char*)sm + 8192 + (p << 12) + (w << 10));
        }
        // assemble scores: one f32x4 read per j, then zero-restore own cells
        float Pw[4][4];
#pragma unroll
        for (int j = 0; j < 4; ++j) {
            const int rr = (j << 4) + ln;
            float* pc = &uwf[(rr << 6) + ((cb ^ (rr & 15)) << 2)];
            const floatx4 s4 = *(const floatx4*)pc;
            *(floatx4*)pc = (floatx4){0.f, 0.f, 0.f, 0.f};
#pragma unroll
            for (int q = 0; q < 4; ++q)
                S[j][q] += s4[q] + mk4[j];
        }
        // online softmax (unconditional rescale — proven form)
#pragma unroll
        for (int q = 0; q < 4; ++q) {
            float tm = fmaxf(fmaxf(S[0][q], S[1][q]), fmaxf(S[2][q], S[3][q]));
            tm = fmaxf(tm, __shfl_xor(tm, 1));
            tm = fmaxf(tm, __shfl_xor(tm, 2));
            tm = fmaxf(tm, __shfl_xor(tm, 4));
            tm = fmaxf(tm, __shfl_xor(tm, 8));
            const float mnew = fmaxf(mr[q], tm);
            const float al = __expf(mr[q] - mnew);
            float sum = 0.f;
#pragma unroll
            for (int j = 0; j < 4; ++j) {
                const float p = __expf(S[j][q] - mnew);
                Pw[j][q] = p; sum += p;
            }
            sum += __shfl_xor(sum, 1);
            sum += __shfl_xor(sum, 2);
            sum += __shfl_xor(sum, 4);
            sum += __shfl_xor(sum, 8);
            lr[q] = lr[q] * al + sum;
            mr[q] = mnew;
#pragma unroll
            for (int dt = 0; dt < 4; ++dt) O[dt][q] *= al;
        }
        // write P (bf16) into [l][r] swizzled tile over dead K (base 0)
#pragma unroll
        for (int j = 0; j < 4; ++j) {
            const int rr = (j << 4) + ln;
#pragma unroll
            for (int q = 0; q < 4; ++q) {
                const int l = x0 + q;
                sm[(l << 6) + ((((rr >> 3) ^ (l & 7)) << 3)) + (rr & 7)] = f2b(Pw[j][q]);
            }
        }
        __syncthreads();                         // D: P + V visible

        const int pr = (w << 4) + ln;
        const short8 pa0 = *(const short8*)&sm[TADDR(0, pr, g)];
        const short8 pa1 = *(const short8*)&sm[TADDR(0, pr, 4 + g)];
        __builtin_amdgcn_s_setprio(1);
#pragma unroll
        for (int dt = 0; dt < 4; ++dt) {
            const int vr = (dt << 4) + ln;       // = d row of V^T tile
            const short8 v0 = *(const short8*)&sm[TADDR(4096, vr, g)];
            const short8 v1 = *(const short8*)&sm[TADDR(4096, vr, 4 + g)];
            O[dt] = __builtin_amdgcn_mfma_f32_16x16x32_bf16(pa0, v0, O[dt], 0, 0, 0);
            O[dt] = __builtin_amdgcn_mfma_f32_16x16x32_bf16(pa1, v1, O[dt], 0, 0, 0);
        }
        __builtin_amdgcn_s_setprio(0);
    }
    // normalize + write out[b, l0+l, h*64 + d]
#pragma unroll
    for (int dt = 0; dt < 4; ++dt)
#pragma unroll
        for (int q = 0; q < 4; ++q) {
            const int l = x0 + q;
            outp[((size_t)b << 20) + ((size_t)(l0 + l) << 10) + (h << 6) + (dt << 4) + ln]
                = O[dt][q] / lr[q];
        }
}

extern "C" void kernel_launch(void* const* d_in, const int* in_sizes, int n_in,
                              void* d_out, int out_size, void* d_ws, size_t ws_size,
                              hipStream_t stream)
{
    const float* hs   = (const float*)d_in[0];   // [4,1024,1024]
    const float* qkvw = (const float*)d_in[1];   // [3072,1024]
    const float* qkvb = (const float*)d_in[2];   // [3072]
    const float* demb = (const float*)d_in[3];   // [2047,64]
    const float* mask = (const float*)d_in[4];   // [4,1,1,1024]
    float* out = (float*)d_out;

    char* ws = (char*)d_ws;
    unsigned short* hsb = (unsigned short*)(ws);              // 8,388,608 B
    unsigned short* Wb  = (unsigned short*)(ws + 8388608);    // 6,291,456 B
    unsigned short* Eb  = (unsigned short*)(ws + 14680064);   //   262,016 B
    unsigned short* Qb  = (unsigned short*)(ws + 14942208);   // 8,388,608 B (pre-scaled)
    unsigned short* Kb  = (unsigned short*)(ws + 23330816);   // 8,388,608 B
    unsigned short* Vt  = (unsigned short*)(ws + 31719424);   // 8,388,608 B (transposed)

    cast_kernel<<<2048, 256, 0, stream>>>(hs, qkvw, demb, hsb, Wb, Eb);
    qkv_gemm<<<dim3(24, 32), 256, 0, stream>>>(hsb, Wb, qkvb, Qb, Kb, Vt);
    attn_mfma<<<1024, 256, 0, stream>>>(Qb, Kb, Vt, Eb, mask, out);
}

// Round 7
// 424.901 us; speedup vs baseline: 2.0601x; 2.0601x over previous
//
#include <hip/hip_runtime.h>

#define SEQ 1024
#define NH  16

typedef __attribute__((ext_vector_type(8))) short short8;
typedef __attribute__((ext_vector_type(4))) float floatx4;
typedef __attribute__((ext_vector_type(4))) unsigned short ushortx4;

// async global->LDS, 16B per lane; LDS dest = wave-uniform base + lane*16
#define GLDS16(gp, lp) __builtin_amdgcn_global_load_lds( \
    (const __attribute__((address_space(1))) void*)(gp), \
    (__attribute__((address_space(3))) void*)(lp), 16, 0, 0)

__device__ __forceinline__ unsigned short f2b(float f) {   // fp32 -> bf16 RNE
    union { float f; unsigned u; } v; v.f = f;
    unsigned r = (v.u + 0x7fffu + ((v.u >> 16) & 1u)) >> 16;
    return (unsigned short)r;
}
__device__ __forceinline__ float b2f(unsigned short h) {
    union { unsigned u; float f; } v; v.u = ((unsigned)h) << 16;
    return v.f;
}

// swizzled addr helper (element offsets in a 64-wide bf16 tile: 8 chunks of 16B/row)
#define TADDR(base, row, ch) ((base) + ((row) << 6) + ((((ch) ^ ((row) & 7))) << 3))

// ---------------- k0: fp32 -> bf16 casts ----------------
__global__ void cast_kernel(const float* __restrict__ hs, const float* __restrict__ W,
                            const float* __restrict__ E,
                            unsigned short* __restrict__ hsb,
                            unsigned short* __restrict__ Wb,
                            unsigned short* __restrict__ Eb)
{
    const int QH = 1048576, QW = 786432, QE = 32752;   // quads
    const int NT = QH + QW + QE;
    for (int q = blockIdx.x * 256 + threadIdx.x; q < NT; q += gridDim.x * 256) {
        const float* src; unsigned short* dst; int off;
        if (q < QH)           { src = hs; dst = hsb; off = q; }
        else if (q < QH + QW) { src = W;  dst = Wb;  off = q - QH; }
        else                  { src = E;  dst = Eb;  off = q - QH - QW; }
        const float4 v = *(const float4*)(src + (size_t)off * 4);
        ushortx4 o; o[0] = f2b(v.x); o[1] = f2b(v.y); o[2] = f2b(v.z); o[3] = f2b(v.w);
        *(ushortx4*)(dst + (size_t)off * 4) = o;
    }
}

// ---------------- k1: QKV projection, bf16 MFMA, NT layout ----------------
__global__ __launch_bounds__(256, 3) void qkv_gemm(
    const unsigned short* __restrict__ Ab, const unsigned short* __restrict__ Bb,
    const float* __restrict__ bias,
    unsigned short* __restrict__ Qb, unsigned short* __restrict__ Kb,
    unsigned short* __restrict__ Vt)
{
    __shared__ unsigned short sm[8192];          // A [0,4096), B [4096,8192) elems
    const int t = threadIdx.x, w = t >> 6;
    const int ln = t & 15, g = (t >> 4) & 3;
    const int wm = w >> 1, wn = w & 1;
    const int m0 = blockIdx.y << 7, o0 = blockIdx.x << 7;

    floatx4 acc[4][4];
#pragma unroll
    for (int i = 0; i < 4; ++i)
#pragma unroll
        for (int j = 0; j < 4; ++j) acc[i][j] = (floatx4){0.f, 0.f, 0.f, 0.f};

    auto stage = [&](int kb) {
#pragma unroll
        for (int p = 0; p < 2; ++p) {
            const int idx = (p << 8) + t;
            const int row = idx >> 2;
            const int c = (idx & 3) ^ ((row ^ (row >> 2)) & 3);
            GLDS16(Ab + (size_t)(m0 + row) * 1024 + kb + (c << 3),
                   (char*)sm + (p << 12) + (w << 10));
            GLDS16(Bb + (size_t)(o0 + row) * 1024 + kb + (c << 3),
                   (char*)sm + 8192 + (p << 12) + (w << 10));
        }
    };

    stage(0);
    for (int kb = 0;;) {
        __syncthreads();
        short8 af[4], bf_[4];
#pragma unroll
        for (int i = 0; i < 4; ++i) {
            const int r = (wm << 6) + (i << 4) + ln;
            af[i] = *(const short8*)&sm[(r << 5) + ((g ^ ((r ^ (r >> 2)) & 3)) << 3)];
        }
#pragma unroll
        for (int j = 0; j < 4; ++j) {
            const int r = (wn << 6) + (j << 4) + ln;
            bf_[j] = *(const short8*)&sm[4096 + (r << 5) + ((g ^ ((r ^ (r >> 2)) & 3)) << 3)];
        }
#pragma unroll
        for (int i = 0; i < 4; ++i)
#pragma unroll
            for (int j = 0; j < 4; ++j)
                acc[i][j] = __builtin_amdgcn_mfma_f32_16x16x32_bf16(af[i], bf_[j], acc[i][j], 0, 0, 0);
        kb += 32;
        if (kb >= 1024) break;
        __syncthreads();
        stage(kb);
    }

    const int which = o0 >> 10;     // 0=Q 1=K 2=V (block-uniform)
    float bj[4];
#pragma unroll
    for (int j = 0; j < 4; ++j) bj[j] = bias[o0 + (wn << 6) + (j << 4) + ln];

    if (which == 2) {               // V transposed: Vt[bh][d][s]
#pragma unroll
        for (int i = 0; i < 4; ++i) {
            const int m = m0 + (wm << 6) + (i << 4) + (g << 2);
            const int b = m >> 10, s = m & 1023;
#pragma unroll
            for (int j = 0; j < 4; ++j) {
                const int o = o0 + (wn << 6) + (j << 4) + ln;
                const int d = o & 63, hh = (o >> 6) & 15;
                ushortx4 pk;
#pragma unroll
                for (int q = 0; q < 4; ++q) pk[q] = f2b(acc[i][j][q] + bj[j]);
                *(ushortx4*)(Vt + (((size_t)((b << 4) + hh)) << 16) + (d << 10) + s) = pk;
            }
        }
    } else {
        unsigned short* dst = which ? Kb : Qb;
        const float sc = which ? 1.0f : 0.125f;   // fold 1/sqrt(64) into Q
#pragma unroll
        for (int i = 0; i < 4; ++i)
#pragma unroll
            for (int q = 0; q < 4; ++q) {
                const int m = m0 + (wm << 6) + (i << 4) + (g << 2) + q;
                const int b = m >> 10, s = m & 1023;
#pragma unroll
                for (int j = 0; j < 4; ++j) {
                    const int o = o0 + (wn << 6) + (j << 4) + ln;
                    const int d = o & 63, hh = (o >> 6) & 15;
                    dst[(((size_t)((b << 4) + hh)) << 16) + (s << 6) + d] =
                        f2b((acc[i][j][q] + bj[j]) * sc);
                }
            }
    }
}

// ---------------- k2: flash attention, 40 KiB LDS -> 4 blocks/CU ----------------
// R2 skeleton (4 barriers/tile, full K/E restage, V over dead E), R6's proven
// liveness overlays (P over dead K, mask hoist, setprio), and PLAIN predicated
// stores (no atomics, no RMW) into two 64x64 bf16 XOR-swizzled U'/W' buffers:
//   U'[r][l] = Q[l]·E[l-r+63]   W'[r][l] = K[r]·E[l-r+63] * 0.125
//   cell addr = (r<<6) + (((l>>2) ^ (r&15))<<2) + (l&3)   (bijective per row)
// Out-of-band shear cells are exec-predicated off; every read cell is written
// every tile (dt-window coverage verified), so no zeroing needed.
// dt pruning: U needs dt in [w,w+4], W needs dt in [3-w,7-w]  (20 MFMA vs 32).
// LDS elems (u16): K[0,4096)+P overlay | E[4096,12288) (V overlays [4096,8192) at C)
//                  U'[12288,16384) | W'[16384,20480)
// total 20480 elems = 40960 B exactly -> 4 blocks/CU (grid 1024 = 256x4, zero tail)
__global__ __launch_bounds__(256, 4) void attn_mfma(
    const unsigned short* __restrict__ Qb, const unsigned short* __restrict__ Kb,
    const unsigned short* __restrict__ Vt, const unsigned short* __restrict__ Eb,
    const float* __restrict__ mask, float* __restrict__ outp)
{
    __shared__ __align__(16) unsigned short sm[20480];
    const int t = threadIdx.x, w = t >> 6;
    const int wu = __builtin_amdgcn_readfirstlane(w);   // wave-uniform in SGPR
    const int ln = t & 15, g = (t >> 4) & 3;
    const int bid = blockIdx.x;
    const int swz = ((bid & 7) << 7) | (bid >> 3);      // XCD-bijective (1024%8==0)
    const int bh = swz >> 4;
    const int l0 = (swz & 15) << 6;
    const int b = bh >> 4, h = bh & 15;
    const size_t hb = (size_t)bh << 16;
    const int x0 = (w << 4) + (g << 2);          // thread's base l-col (U) / r-row (W)
    const int cb = x0 >> 2;                      // col-granule for the XOR swizzle

    // Q fragments direct from global (pre-scaled; L2-hot)
    const int qr = (w << 4) + ln;
    const short8 qa0 = *(const short8*)(Qb + hb + ((size_t)(l0 + qr) << 6) + (g << 3));
    const short8 qa1 = *(const short8*)(Qb + hb + ((size_t)(l0 + qr) << 6) + 32 + (g << 3));

    floatx4 O[4];
    float mr[4], lr[4];
#pragma unroll
    for (int dt = 0; dt < 4; ++dt) O[dt] = (floatx4){0.f, 0.f, 0.f, 0.f};
#pragma unroll
    for (int q = 0; q < 4; ++q) { mr[q] = -1e30f; lr[q] = 0.f; }

    for (int r0 = 0; r0 < SEQ; r0 += 64) {
        // hoist mask loads (consumed ~1.5k cyc later in scores)
        float mk4[4];
#pragma unroll
        for (int j = 0; j < 4; ++j) mk4[j] = mask[(b << 10) + r0 + (j << 4) + ln];

        __syncthreads();                         // A: prev PV/P reads done
#pragma unroll
        for (int p = 0; p < 2; ++p) {            // stage K at elem 0
            const int idx = (p << 8) + t;
            const int row = idx >> 3;
            const int c = (idx & 7) ^ (row & 7);
            GLDS16(Kb + hb + ((size_t)(r0 + row) << 6) + (c << 3),
                   (char*)sm + (p << 12) + (w << 10));
        }
        const int j0 = l0 - r0 + 960;            // E band start, in [0,1920]
#pragma unroll
        for (int p = 0; p < 4; ++p) {            // stage E (128 rows) at elem 4096
            const int idx = (p << 8) + t;
            const int row = idx >> 3;
            const int c = (idx & 7) ^ (row & 7);
            GLDS16(Eb + ((size_t)(j0 + row) << 6) + (c << 3),
                   (char*)sm + 8192 + (p << 12) + (w << 10));
        }
        __syncthreads();                         // B: staging visible

        short8 kf[4][2];
#pragma unroll
        for (int j = 0; j < 4; ++j) {
            const int kr = (j << 4) + ln;
            kf[j][0] = *(const short8*)&sm[TADDR(0, kr, g)];
            kf[j][1] = *(const short8*)&sm[TADDR(0, kr, 4 + g)];
        }
        const int wr = (w << 4) + ln;            // W A-fragment (this wave's K rows)
        const short8 ka0 = *(const short8*)&sm[TADDR(0, wr, g)];
        const short8 ka1 = *(const short8*)&sm[TADDR(0, wr, 4 + g)];

        __builtin_amdgcn_s_setprio(1);
        floatx4 S[4];
#pragma unroll
        for (int j = 0; j < 4; ++j) {
            floatx4 z = (floatx4){0.f, 0.f, 0.f, 0.f};
            z = __builtin_amdgcn_mfma_f32_16x16x32_bf16(qa0, kf[j][0], z, 0, 0, 0);
            S[j] = __builtin_amdgcn_mfma_f32_16x16x32_bf16(qa1, kf[j][1], z, 0, 0, 0);
        }
        // band GEMMs, pruned per wave; predicated plain stores into U'/W'
#pragma unroll
        for (int dt = 0; dt < 8; ++dt) {
            const bool doU = (dt >= wu) && (dt <= wu + 4);
            const bool doW = (dt >= 3 - wu) && (dt <= 7 - wu);
            if (!doU && !doW) continue;
            const int er = (dt << 4) + ln;
            const short8 e0 = *(const short8*)&sm[TADDR(4096, er, g)];
            const short8 e1 = *(const short8*)&sm[TADDR(4096, er, 4 + g)];
            if (doU) {
                floatx4 z = (floatx4){0.f, 0.f, 0.f, 0.f};
                z = __builtin_amdgcn_mfma_f32_16x16x32_bf16(qa0, e0, z, 0, 0, 0);
                const floatx4 U = __builtin_amdgcn_mfma_f32_16x16x32_bf16(qa1, e1, z, 0, 0, 0);
#pragma unroll
                for (int q = 0; q < 4; ++q) {
                    const int ru = x0 + q - (dt << 4) - ln + 63;   // cell (ru, l=x0+q)
                    if ((unsigned)ru < 64u)
                        sm[12288 + (ru << 6) + ((cb ^ (ru & 15)) << 2) + q] = f2b(U[q]);
                }
            }
            if (doW) {
                floatx4 z2 = (floatx4){0.f, 0.f, 0.f, 0.f};
                z2 = __builtin_amdgcn_mfma_f32_16x16x32_bf16(ka0, e0, z2, 0, 0, 0);
                const floatx4 Wv = __builtin_amdgcn_mfma_f32_16x16x32_bf16(ka1, e1, z2, 0, 0, 0);
#pragma unroll
                for (int q = 0; q < 4; ++q) {
                    const int r = x0 + q;                          // cell (r, lw)
                    const int lw = (dt << 4) + ln + r - 63;
                    if ((unsigned)lw < 64u)
                        sm[16384 + (r << 6) + (((lw >> 2) ^ (r & 15)) << 2) + (lw & 3)]
                            = f2b(Wv[q] * 0.125f);
                }
            }
        }
        __builtin_amdgcn_s_setprio(0);
        __syncthreads();                         // C: U'/W' visible; K, E dead

#pragma unroll
        for (int p = 0; p < 2; ++p) {            // stage V (transposed) over dead E
            const int idx = (p << 8) + t;
            const int row = idx >> 3;            // = d
            const int c = (idx & 7) ^ (row & 7);
            GLDS16(Vt + hb + ((size_t)row << 10) + r0 + (c << 3),
                   (char*)sm + 8192 + (p << 12) + (w << 10));
        }
        // assemble scores: one b64 read per term per j
        float Pw[4][4];
#pragma unroll
        for (int j = 0; j < 4; ++j) {
            const int rr = (j << 4) + ln;
            const int sa = (rr << 6) + ((cb ^ (rr & 15)) << 2);
            const ushortx4 u4 = *(const ushortx4*)&sm[12288 + sa];
            const ushortx4 w4 = *(const ushortx4*)&sm[16384 + sa];
#pragma unroll
            for (int q = 0; q < 4; ++q)
                S[j][q] += b2f(u4[q]) + b2f(w4[q]) + mk4[j];
        }
        // online softmax (unconditional rescale — proven form)
#pragma unroll
        for (int q = 0; q < 4; ++q) {
            float tm = fmaxf(fmaxf(S[0][q], S[1][q]), fmaxf(S[2][q], S[3][q]));
            tm = fmaxf(tm, __shfl_xor(tm, 1));
            tm = fmaxf(tm, __shfl_xor(tm, 2));
            tm = fmaxf(tm, __shfl_xor(tm, 4));
            tm = fmaxf(tm, __shfl_xor(tm, 8));
            const float mnew = fmaxf(mr[q], tm);
            const float al = __expf(mr[q] - mnew);
            float sum = 0.f;
#pragma unroll
            for (int j = 0; j < 4; ++j) {
                const float p = __expf(S[j][q] - mnew);
                Pw[j][q] = p; sum += p;
            }
            sum += __shfl_xor(sum, 1);
            sum += __shfl_xor(sum, 2);
            sum += __shfl_xor(sum, 4);
            sum += __shfl_xor(sum, 8);
            lr[q] = lr[q] * al + sum;
            mr[q] = mnew;
#pragma unroll
            for (int dt = 0; dt < 4; ++dt) O[dt][q] *= al;
        }
        // write P (bf16) into [l][r] swizzled tile over dead K (base 0)
#pragma unroll
        for (int j = 0; j < 4; ++j) {
            const int rr = (j << 4) + ln;
#pragma unroll
            for (int q = 0; q < 4; ++q) {
                const int l = x0 + q;
                sm[(l << 6) + ((((rr >> 3) ^ (l & 7)) << 3)) + (rr & 7)] = f2b(Pw[j][q]);
            }
        }
        __syncthreads();                         // D: P + V visible

        const int pr = (w << 4) + ln;
        const short8 pa0 = *(const short8*)&sm[TADDR(0, pr, g)];
        const short8 pa1 = *(const short8*)&sm[TADDR(0, pr, 4 + g)];
        __builtin_amdgcn_s_setprio(1);
#pragma unroll
        for (int dt = 0; dt < 4; ++dt) {
            const int vr = (dt << 4) + ln;       // = d row of V^T tile
            const short8 v0 = *(const short8*)&sm[TADDR(4096, vr, g)];
            const short8 v1 = *(const short8*)&sm[TADDR(4096, vr, 4 + g)];
            O[dt] = __builtin_amdgcn_mfma_f32_16x16x32_bf16(pa0, v0, O[dt], 0, 0, 0);
            O[dt] = __builtin_amdgcn_mfma_f32_16x16x32_bf16(pa1, v1, O[dt], 0, 0, 0);
        }
        __builtin_amdgcn_s_setprio(0);
    }
    // normalize + write out[b, l0+l, h*64 + d]
#pragma unroll
    for (int dt = 0; dt < 4; ++dt)
#pragma unroll
        for (int q = 0; q < 4; ++q) {
            const int l = x0 + q;
            outp[((size_t)b << 20) + ((size_t)(l0 + l) << 10) + (h << 6) + (dt << 4) + ln]
                = O[dt][q] / lr[q];
        }
}

extern "C" void kernel_launch(void* const* d_in, const int* in_sizes, int n_in,
                              void* d_out, int out_size, void* d_ws, size_t ws_size,
                              hipStream_t stream)
{
    const float* hs   = (const float*)d_in[0];   // [4,1024,1024]
    const float* qkvw = (const float*)d_in[1];   // [3072,1024]
    const float* qkvb = (const float*)d_in[2];   // [3072]
    const float* demb = (const float*)d_in[3];   // [2047,64]
    const float* mask = (const float*)d_in[4];   // [4,1,1,1024]
    float* out = (float*)d_out;

    char* ws = (char*)d_ws;
    unsigned short* hsb = (unsigned short*)(ws);              // 8,388,608 B
    unsigned short* Wb  = (unsigned short*)(ws + 8388608);    // 6,291,456 B
    unsigned short* Eb  = (unsigned short*)(ws + 14680064);   //   262,016 B
    unsigned short* Qb  = (unsigned short*)(ws + 14942208);   // 8,388,608 B (pre-scaled)
    unsigned short* Kb  = (unsigned short*)(ws + 23330816);   // 8,388,608 B
    unsigned short* Vt  = (unsigned short*)(ws + 31719424);   // 8,388,608 B (transposed)

    cast_kernel<<<2048, 256, 0, stream>>>(hs, qkvw, demb, hsb, Wb, Eb);
    qkv_gemm<<<dim3(24, 32), 256, 0, stream>>>(hsb, Wb, qkvb, Qb, Kb, Vt);
    attn_mfma<<<1024, 256, 0, stream>>>(Qb, Kb, Vt, Eb, mask, out);
}

// Round 9
// 234.517 us; speedup vs baseline: 3.7325x; 1.8118x over previous
//
#include <hip/hip_runtime.h>

#define SEQ 1024
#define NH  16

typedef __attribute__((ext_vector_type(8))) short short8;
typedef __attribute__((ext_vector_type(4))) float floatx4;
typedef __attribute__((ext_vector_type(4))) unsigned short ushortx4;

// async global->LDS, 16B per lane; LDS dest = wave-uniform base + lane*16
#define GLDS16(gp, lp) __builtin_amdgcn_global_load_lds( \
    (const __attribute__((address_space(1))) void*)(gp), \
    (__attribute__((address_space(3))) void*)(lp), 16, 0, 0)

__device__ __forceinline__ unsigned short f2b(float f) {   // fp32 -> bf16 RNE
    union { float f; unsigned u; } v; v.f = f;
    unsigned r = (v.u + 0x7fffu + ((v.u >> 16) & 1u)) >> 16;
    return (unsigned short)r;
}
__device__ __forceinline__ float b2f(unsigned short h) {
    union { unsigned u; float f; } v; v.u = ((unsigned)h) << 16;
    return v.f;
}

// swizzled addr helper (element offsets in a 64-wide bf16 tile: 8 chunks of 16B/row)
#define TADDR(base, row, ch) ((base) + ((row) << 6) + ((((ch) ^ ((row) & 7))) << 3))

// ---------------- k0: fp32 -> bf16 casts ----------------
__global__ void cast_kernel(const float* __restrict__ hs, const float* __restrict__ W,
                            const float* __restrict__ E,
                            unsigned short* __restrict__ hsb,
                            unsigned short* __restrict__ Wb,
                            unsigned short* __restrict__ Eb)
{
    const int QH = 1048576, QW = 786432, QE = 32752;   // quads
    const int NT = QH + QW + QE;
    for (int q = blockIdx.x * 256 + threadIdx.x; q < NT; q += gridDim.x * 256) {
        const float* src; unsigned short* dst; int off;
        if (q < QH)           { src = hs; dst = hsb; off = q; }
        else if (q < QH + QW) { src = W;  dst = Wb;  off = q - QH; }
        else                  { src = E;  dst = Eb;  off = q - QH - QW; }
        const float4 v = *(const float4*)(src + (size_t)off * 4);
        ushortx4 o; o[0] = f2b(v.x); o[1] = f2b(v.y); o[2] = f2b(v.z); o[3] = f2b(v.w);
        *(ushortx4*)(dst + (size_t)off * 4) = o;
    }
}

// ---------------- k1: QKV projection — 2-phase double-buffered K-loop ----------------
// T3-minimum pipeline: stage(t+1) into buf^1 issued BEFORE compute(t) on buf;
// single __syncthreads per K-step (drains both GLDS and LDS reads).
// LDS: 2 buffers x (A 4096 + B 4096) elems = 32 KiB.
__global__ __launch_bounds__(256, 3) void qkv_gemm(
    const unsigned short* __restrict__ Ab, const unsigned short* __restrict__ Bb,
    const float* __restrict__ bias,
    unsigned short* __restrict__ Qb, unsigned short* __restrict__ Kb,
    unsigned short* __restrict__ Vt)
{
    __shared__ unsigned short sm[16384];
    const int t = threadIdx.x, w = t >> 6;
    const int ln = t & 15, g = (t >> 4) & 3;
    const int wm = w >> 1, wn = w & 1;
    // XCD-chunked swizzle: 768 wgs = 8 XCDs x 96; chunk shares A-panels (4 by-rows)
    const int bid = blockIdx.x + blockIdx.y * 24;
    const int swzid = (bid & 7) * 96 + (bid >> 3);
    const int m0 = (swzid / 24) << 7, o0 = (swzid % 24) << 7;

    floatx4 acc[4][4];
#pragma unroll
    for (int i = 0; i < 4; ++i)
#pragma unroll
        for (int j = 0; j < 4; ++j) acc[i][j] = (floatx4){0.f, 0.f, 0.f, 0.f};

    auto stage = [&](int kb, int buf) {
        const int base = buf << 14;              // bytes
#pragma unroll
        for (int p = 0; p < 2; ++p) {
            const int idx = (p << 8) + t;
            const int row = idx >> 2;
            const int c = (idx & 3) ^ ((row ^ (row >> 2)) & 3);
            GLDS16(Ab + (size_t)(m0 + row) * 1024 + kb + (c << 3),
                   (char*)sm + base + (p << 12) + (w << 10));
            GLDS16(Bb + (size_t)(o0 + row) * 1024 + kb + (c << 3),
                   (char*)sm + base + 8192 + (p << 12) + (w << 10));
        }
    };

    stage(0, 0);
    __syncthreads();
    int buf = 0;
    for (int kb = 0; kb < 1024; kb += 32) {
        if (kb + 32 < 1024) stage(kb + 32, buf ^ 1);   // issue next-tile loads early
        const int be = buf << 13;                      // elems
        short8 af[4], bf_[4];
#pragma unroll
        for (int i = 0; i < 4; ++i) {
            const int r = (wm << 6) + (i << 4) + ln;
            af[i] = *(const short8*)&sm[be + (r << 5) + ((g ^ ((r ^ (r >> 2)) & 3)) << 3)];
        }
#pragma unroll
        for (int j = 0; j < 4; ++j) {
            const int r = (wn << 6) + (j << 4) + ln;
            bf_[j] = *(const short8*)&sm[be + 4096 + (r << 5) + ((g ^ ((r ^ (r >> 2)) & 3)) << 3)];
        }
#pragma unroll
        for (int i = 0; i < 4; ++i)
#pragma unroll
            for (int j = 0; j < 4; ++j)
                acc[i][j] = __builtin_amdgcn_mfma_f32_16x16x32_bf16(af[i], bf_[j], acc[i][j], 0, 0, 0);
        __syncthreads();                               // drains GLDS + syncs reads
        buf ^= 1;
    }

    const int which = o0 >> 10;     // 0=Q 1=K 2=V (block-uniform)
    float bj[4];
#pragma unroll
    for (int j = 0; j < 4; ++j) bj[j] = bias[o0 + (wn << 6) + (j << 4) + ln];

    if (which == 2) {               // V transposed: Vt[bh][d][s]
#pragma unroll
        for (int i = 0; i < 4; ++i) {
            const int m = m0 + (wm << 6) + (i << 4) + (g << 2);
            const int b = m >> 10, s = m & 1023;
#pragma unroll
            for (int j = 0; j < 4; ++j) {
                const int o = o0 + (wn << 6) + (j << 4) + ln;
                const int d = o & 63, hh = (o >> 6) & 15;
                ushortx4 pk;
#pragma unroll
                for (int q = 0; q < 4; ++q) pk[q] = f2b(acc[i][j][q] + bj[j]);
                *(ushortx4*)(Vt + (((size_t)((b << 4) + hh)) << 16) + (d << 10) + s) = pk;
            }
        }
    } else {
        unsigned short* dst = which ? Kb : Qb;
        const float sc = which ? 1.0f : 0.125f;   // fold 1/sqrt(64) into Q
#pragma unroll
        for (int i = 0; i < 4; ++i)
#pragma unroll
            for (int q = 0; q < 4; ++q) {
                const int m = m0 + (wm << 6) + (i << 4) + (g << 2) + q;
                const int b = m >> 10, s = m & 1023;
#pragma unroll
                for (int j = 0; j < 4; ++j) {
                    const int o = o0 + (wn << 6) + (j << 4) + ln;
                    const int d = o & 63, hh = (o >> 6) & 15;
                    dst[(((size_t)((b << 4) + hh)) << 16) + (s << 6) + d] =
                        f2b((acc[i][j][q] + bj[j]) * sc);
                }
            }
    }
}

// ---------------- k2: flash attention (R2-proven structure + mask hoist + setprio) ----------------
// block = 4 waves, (bh, 64 l-rows); wave w owns l-rows [16w,16w+16)
// per 64-key tile: S = QK^T + Uterm + Wterm, U/W pre-sheared into S-layout buffers.
// dt pruning: U needs dt in [w,w+4], W needs dt in [3-w,7-w]  (20 MFMA vs 32).
// LDS elems (u16): K[0,4096) | E[4096,12288) -> V[4096,8192)+P[8192,12288)
//                  U'[12288,19200) rows=(rr+16) in [0,96), stride 72
//                  W'[19200,25600) rows=rr in [0,64), stride 100 (cols ll+16)
// total 25600 elems = 50 KiB -> 3 blocks/CU
__global__ __launch_bounds__(256, 3) void attn_mfma(
    const unsigned short* __restrict__ Qb, const unsigned short* __restrict__ Kb,
    const unsigned short* __restrict__ Vt, const unsigned short* __restrict__ Eb,
    const float* __restrict__ mask, float* __restrict__ outp)
{
    __shared__ __align__(16) unsigned short sm[25600];
    const int t = threadIdx.x, w = t >> 6;
    const int wu = __builtin_amdgcn_readfirstlane(w);   // wave-uniform in SGPR
    const int ln = t & 15, g = (t >> 4) & 3;
    const int bid = blockIdx.x;
    const int swz = ((bid & 7) << 7) | (bid >> 3);      // XCD-bijective (1024%8==0)
    const int bh = swz >> 4;
    const int l0 = (swz & 15) << 6;
    const int b = bh >> 4, h = bh & 15;
    const size_t hb = (size_t)bh << 16;
    const int x0 = (w << 4) + (g << 2);          // thread's base l-row

    // Q fragments direct from global (pre-scaled; read once, L2-hot)
    const int qr = (w << 4) + ln;
    const short8 qa0 = *(const short8*)(Qb + hb + ((size_t)(l0 + qr) << 6) + (g << 3));
    const short8 qa1 = *(const short8*)(Qb + hb + ((size_t)(l0 + qr) << 6) + 32 + (g << 3));

    floatx4 O[4];
    float mr[4], lr[4];
#pragma unroll
    for (int dt = 0; dt < 4; ++dt) O[dt] = (floatx4){0.f, 0.f, 0.f, 0.f};
#pragma unroll
    for (int q = 0; q < 4; ++q) { mr[q] = -1e30f; lr[q] = 0.f; }

    for (int r0 = 0; r0 < SEQ; r0 += 64) {
        // hoist mask loads: consumed ~1.5k cyc later in score assembly
        float mk4[4];
#pragma unroll
        for (int j = 0; j < 4; ++j) mk4[j] = mask[(b << 10) + r0 + (j << 4) + ln];

        __syncthreads();                         // A: prev PV/V reads done
#pragma unroll
        for (int p = 0; p < 2; ++p) {            // stage K at elems [0,4096)
            const int idx = (p << 8) + t;
            const int row = idx >> 3;
            const int c = (idx & 7) ^ (row & 7);
            GLDS16(Kb + hb + ((size_t)(r0 + row) << 6) + (c << 3),
                   (char*)sm + (p << 12) + (w << 10));
        }
        const int j0 = l0 - r0 + 960;            // E band start, in [0,1920]
#pragma unroll
        for (int p = 0; p < 4; ++p) {            // stage E band (128 rows) at elems [4096,12288)
            const int idx = (p << 8) + t;
            const int row = idx >> 3;
            const int c = (idx & 7) ^ (row & 7);
            GLDS16(Eb + ((size_t)(j0 + row) << 6) + (c << 3),
                   (char*)sm + 8192 + (p << 12) + (w << 10));
        }
        __syncthreads();                         // B: staging visible
        short8 kf[4][2];
#pragma unroll
        for (int j = 0; j < 4; ++j) {
            const int kr = (j << 4) + ln;
            kf[j][0] = *(const short8*)&sm[TADDR(0, kr, g)];
            kf[j][1] = *(const short8*)&sm[TADDR(0, kr, 4 + g)];
        }
        const int wr = (w << 4) + ln;            // W A-fragment (this wave's K rows)
        const short8 ka0 = *(const short8*)&sm[TADDR(0, wr, g)];
        const short8 ka1 = *(const short8*)&sm[TADDR(0, wr, 4 + g)];

        __builtin_amdgcn_s_setprio(1);
        floatx4 S[4];
#pragma unroll
        for (int j = 0; j < 4; ++j) {
            floatx4 z = (floatx4){0.f, 0.f, 0.f, 0.f};
            z = __builtin_amdgcn_mfma_f32_16x16x32_bf16(qa0, kf[j][0], z, 0, 0, 0);
            S[j] = __builtin_amdgcn_mfma_f32_16x16x32_bf16(qa1, kf[j][1], z, 0, 0, 0);
        }
        // band GEMMs, pruned per wave; outputs written pre-sheared
#pragma unroll
        for (int dt = 0; dt < 8; ++dt) {
            const bool doU = (dt >= wu) && (dt <= wu + 4);
            const bool doW = (dt >= 3 - wu) && (dt <= 7 - wu);
            if (!doU && !doW) continue;
            const int er = (dt << 4) + ln;
            const short8 e0 = *(const short8*)&sm[TADDR(4096, er, g)];
            const short8 e1 = *(const short8*)&sm[TADDR(4096, er, 4 + g)];
            if (doU) {
                floatx4 z = (floatx4){0.f, 0.f, 0.f, 0.f};
                z = __builtin_amdgcn_mfma_f32_16x16x32_bf16(qa0, e0, z, 0, 0, 0);
                const floatx4 U = __builtin_amdgcn_mfma_f32_16x16x32_bf16(qa1, e1, z, 0, 0, 0);
                // cell (rr = ll-br+63, ll), ll = x0+q, br = 16dt+ln; rr+16 in [0,95]
                int a = 12288 + (x0 - (dt << 4) - ln + 79) * 72 + x0;
#pragma unroll
                for (int q = 0; q < 4; ++q) { sm[a] = f2b(U[q]); a += 73; }
            }
            if (doW) {
                floatx4 z2 = (floatx4){0.f, 0.f, 0.f, 0.f};
                z2 = __builtin_amdgcn_mfma_f32_16x16x32_bf16(ka0, e0, z2, 0, 0, 0);
                const floatx4 Wv = __builtin_amdgcn_mfma_f32_16x16x32_bf16(ka1, e1, z2, 0, 0, 0);
                // cell (rW = x0+q, ll+16 = 16dt+ln+x0+q-47), ll+16 in [1,95]
                int a = 19200 + x0 * 101 + (dt << 4) + ln - 47;
#pragma unroll
                for (int q = 0; q < 4; ++q) { sm[a] = f2b(Wv[q] * 0.125f); a += 101; }
            }
        }
        __builtin_amdgcn_s_setprio(0);
        __syncthreads();                         // C: U'/W' visible; E dead
#pragma unroll
        for (int p = 0; p < 2; ++p) {            // stage V (transposed) over dead E
            const int idx = (p << 8) + t;
            const int row = idx >> 3;            // = d
            const int c = (idx & 7) ^ (row & 7);
            GLDS16(Vt + hb + ((size_t)row << 10) + r0 + (c << 3),
                   (char*)sm + 8192 + (p << 12) + (w << 10));
        }
        // assemble scores: vector b64 reads + hoisted mask
        float Pw[4][4];
#pragma unroll
        for (int j = 0; j < 4; ++j) {
            const int rr = (j << 4) + ln;
            const ushortx4 u4 = *(const ushortx4*)&sm[12288 + (rr + 16) * 72 + x0];
            const ushortx4 w4 = *(const ushortx4*)&sm[19200 + rr * 100 + 16 + x0];
#pragma unroll
            for (int q = 0; q < 4; ++q)
                S[j][q] += b2f(u4[q]) + b2f(w4[q]) + mk4[j];
        }
#pragma unroll
        for (int q = 0; q < 4; ++q) {
            float tm = fmaxf(fmaxf(S[0][q], S[1][q]), fmaxf(S[2][q], S[3][q]));
            tm = fmaxf(tm, __shfl_xor(tm, 1));
            tm = fmaxf(tm, __shfl_xor(tm, 2));
            tm = fmaxf(tm, __shfl_xor(tm, 4));
            tm = fmaxf(tm, __shfl_xor(tm, 8));
            const float mnew = fmaxf(mr[q], tm);
            const float al = __expf(mr[q] - mnew);
            float sum = 0.f;
#pragma unroll
            for (int j = 0; j < 4; ++j) {
                const float p = __expf(S[j][q] - mnew);
                Pw[j][q] = p; sum += p;
            }
            sum += __shfl_xor(sum, 1);
            sum += __shfl_xor(sum, 2);
            sum += __shfl_xor(sum, 4);
            sum += __shfl_xor(sum, 8);
            lr[q] = lr[q] * al + sum;
            mr[q] = mnew;
#pragma unroll
            for (int dt = 0; dt < 4; ++dt) O[dt][q] *= al;
        }
        // write P (bf16) into [l][r] swizzled tile at elem 8192
#pragma unroll
        for (int j = 0; j < 4; ++j) {
            const int rr = (j << 4) + ln;
#pragma unroll
            for (int q = 0; q < 4; ++q) {
                const int l = x0 + q;
                sm[8192 + (l << 6) + ((((rr >> 3) ^ (l & 7)) << 3)) + (rr & 7)] = f2b(Pw[j][q]);
            }
        }
        __syncthreads();                         // D: P + V visible
        const int pr = (w << 4) + ln;
        const short8 pa0 = *(const short8*)&sm[TADDR(8192, pr, g)];
        const short8 pa1 = *(const short8*)&sm[TADDR(8192, pr, 4 + g)];
        __builtin_amdgcn_s_setprio(1);
#pragma unroll
        for (int dt = 0; dt < 4; ++dt) {
            const int vr = (dt << 4) + ln;       // = d row of V^T tile
            const short8 v0 = *(const short8*)&sm[TADDR(4096, vr, g)];
            const short8 v1 = *(const short8*)&sm[TADDR(4096, vr, 4 + g)];
            O[dt] = __builtin_amdgcn_mfma_f32_16x16x32_bf16(pa0, v0, O[dt], 0, 0, 0);
            O[dt] = __builtin_amdgcn_mfma_f32_16x16x32_bf16(pa1, v1, O[dt], 0, 0, 0);
        }
        __builtin_amdgcn_s_setprio(0);
    }
    // normalize + write out[b, l0+l, h*64 + d]
#pragma unroll
    for (int dt = 0; dt < 4; ++dt)
#pragma unroll
        for (int q = 0; q < 4; ++q) {
            const int l = x0 + q;
            outp[((size_t)b << 20) + ((size_t)(l0 + l) << 10) + (h << 6) + (dt << 4) + ln]
                = O[dt][q] / lr[q];
        }
}

extern "C" void kernel_launch(void* const* d_in, const int* in_sizes, int n_in,
                              void* d_out, int out_size, void* d_ws, size_t ws_size,
                              hipStream_t stream)
{
    const float* hs   = (const float*)d_in[0];   // [4,1024,1024]
    const float* qkvw = (const float*)d_in[1];   // [3072,1024]
    const float* qkvb = (const float*)d_in[2];   // [3072]
    const float* demb = (const float*)d_in[3];   // [2047,64]
    const float* mask = (const float*)d_in[4];   // [4,1,1,1024]
    float* out = (float*)d_out;

    char* ws = (char*)d_ws;
    unsigned short* hsb = (unsigned short*)(ws);              // 8,388,608 B
    unsigned short* Wb  = (unsigned short*)(ws + 8388608);    // 6,291,456 B
    unsigned short* Eb  = (unsigned short*)(ws + 14680064);   //   262,016 B
    unsigned short* Qb  = (unsigned short*)(ws + 14942208);   // 8,388,608 B (pre-scaled)
    unsigned short* Kb  = (unsigned short*)(ws + 23330816);   // 8,388,608 B
    unsigned short* Vt  = (unsigned short*)(ws + 31719424);   // 8,388,608 B (transposed)

    cast_kernel<<<2048, 256, 0, stream>>>(hs, qkvw, demb, hsb, Wb, Eb);
    qkv_gemm<<<dim3(24, 32), 256, 0, stream>>>(hsb, Wb, qkvb, Qb, Kb, Vt);
    attn_mfma<<<1024, 256, 0, stream>>>(Qb, Kb, Vt, Eb, mask, out);
}

// Round 10
// 229.753 us; speedup vs baseline: 3.8099x; 1.0207x over previous
//
#include <hip/hip_runtime.h>

#define SEQ 1024
#define NH  16

typedef __attribute__((ext_vector_type(8))) short short8;
typedef __attribute__((ext_vector_type(4))) float floatx4;
typedef __attribute__((ext_vector_type(4))) unsigned short ushortx4;

// async global->LDS, 16B per lane; LDS dest = wave-uniform base + lane*16
#define GLDS16(gp, lp) __builtin_amdgcn_global_load_lds( \
    (const __attribute__((address_space(1))) void*)(gp), \
    (__attribute__((address_space(3))) void*)(lp), 16, 0, 0)

__device__ __forceinline__ unsigned short f2b(float f) {   // fp32 -> bf16 RNE
    union { float f; unsigned u; } v; v.f = f;
    unsigned r = (v.u + 0x7fffu + ((v.u >> 16) & 1u)) >> 16;
    return (unsigned short)r;
}
__device__ __forceinline__ float b2f(unsigned short h) {
    union { unsigned u; float f; } v; v.u = ((unsigned)h) << 16;
    return v.f;
}

// swizzled addr helper (element offsets in a 64-wide bf16 tile: 8 chunks of 16B/row)
#define TADDR(base, row, ch) ((base) + ((row) << 6) + ((((ch) ^ ((row) & 7))) << 3))

// ---------------- k0: fp32 -> bf16 casts ----------------
__global__ void cast_kernel(const float* __restrict__ hs, const float* __restrict__ W,
                            const float* __restrict__ E,
                            unsigned short* __restrict__ hsb,
                            unsigned short* __restrict__ Wb,
                            unsigned short* __restrict__ Eb)
{
    const int QH = 1048576, QW = 786432, QE = 32752;   // quads
    const int NT = QH + QW + QE;
    for (int q = blockIdx.x * 256 + threadIdx.x; q < NT; q += gridDim.x * 256) {
        const float* src; unsigned short* dst; int off;
        if (q < QH)           { src = hs; dst = hsb; off = q; }
        else if (q < QH + QW) { src = W;  dst = Wb;  off = q - QH; }
        else                  { src = E;  dst = Eb;  off = q - QH - QW; }
        const float4 v = *(const float4*)(src + (size_t)off * 4);
        ushortx4 o; o[0] = f2b(v.x); o[1] = f2b(v.y); o[2] = f2b(v.z); o[3] = f2b(v.w);
        *(ushortx4*)(dst + (size_t)off * 4) = o;
    }
}

// ---------------- k1: QKV projection — 2-phase K-loop + LDS-staged coalesced epilogue ----
// K-loop: stage(t+1) issued before compute(t), one barrier per K-step.
// Epilogue: C-tile (128x128 bf16 = 32KB) staged in the dead K-loop LDS, then
// 8 fully-coalesced 16B global stores per thread (was 64 scalar 2B stores).
__global__ __launch_bounds__(256, 3) void qkv_gemm(
    const unsigned short* __restrict__ Ab, const unsigned short* __restrict__ Bb,
    const float* __restrict__ bias,
    unsigned short* __restrict__ Qb, unsigned short* __restrict__ Kb,
    unsigned short* __restrict__ Vt)
{
    __shared__ unsigned short sm[16384];
    const int t = threadIdx.x, w = t >> 6;
    const int ln = t & 15, g = (t >> 4) & 3;
    const int wm = w >> 1, wn = w & 1;
    // XCD-chunked swizzle: 768 wgs = 8 XCDs x 96
    const int bid = blockIdx.x + blockIdx.y * 24;
    const int swzid = (bid & 7) * 96 + (bid >> 3);
    const int m0 = (swzid / 24) << 7, o0 = (swzid % 24) << 7;

    floatx4 acc[4][4];
#pragma unroll
    for (int i = 0; i < 4; ++i)
#pragma unroll
        for (int j = 0; j < 4; ++j) acc[i][j] = (floatx4){0.f, 0.f, 0.f, 0.f};

    auto stage = [&](int kb, int buf) {
        const int base = buf << 14;              // bytes
#pragma unroll
        for (int p = 0; p < 2; ++p) {
            const int idx = (p << 8) + t;
            const int row = idx >> 2;
            const int c = (idx & 3) ^ ((row ^ (row >> 2)) & 3);
            GLDS16(Ab + (size_t)(m0 + row) * 1024 + kb + (c << 3),
                   (char*)sm + base + (p << 12) + (w << 10));
            GLDS16(Bb + (size_t)(o0 + row) * 1024 + kb + (c << 3),
                   (char*)sm + base + 8192 + (p << 12) + (w << 10));
        }
    };

    stage(0, 0);
    __syncthreads();
    int buf = 0;
    for (int kb = 0; kb < 1024; kb += 32) {
        if (kb + 32 < 1024) stage(kb + 32, buf ^ 1);   // issue next-tile loads early
        const int be = buf << 13;                      // elems
        short8 af[4], bf_[4];
#pragma unroll
        for (int i = 0; i < 4; ++i) {
            const int r = (wm << 6) + (i << 4) + ln;
            af[i] = *(const short8*)&sm[be + (r << 5) + ((g ^ ((r ^ (r >> 2)) & 3)) << 3)];
        }
#pragma unroll
        for (int j = 0; j < 4; ++j) {
            const int r = (wn << 6) + (j << 4) + ln;
            bf_[j] = *(const short8*)&sm[be + 4096 + (r << 5) + ((g ^ ((r ^ (r >> 2)) & 3)) << 3)];
        }
#pragma unroll
        for (int i = 0; i < 4; ++i)
#pragma unroll
            for (int j = 0; j < 4; ++j)
                acc[i][j] = __builtin_amdgcn_mfma_f32_16x16x32_bf16(af[i], bf_[j], acc[i][j], 0, 0, 0);
        __syncthreads();                               // drains GLDS + syncs reads
        buf ^= 1;
    }
    // (last barrier above: all staging reads done -> sm reusable for C-tile)

    const int which = o0 >> 10;     // 0=Q 1=K 2=V (block-uniform)
    float bj[4];
#pragma unroll
    for (int j = 0; j < 4; ++j) bj[j] = bias[o0 + (wn << 6) + (j << 4) + ln];
    const int b0 = m0 >> 10;        // tile stays within one batch (128 | 1024)

    if (which == 2) {
        // V: LDS transposed tile, elem(oi,mi) = oi*128 + ((mi>>3)^(oi&15))*8 + (mi&7)
#pragma unroll
        for (int i = 0; i < 4; ++i)
#pragma unroll
            for (int j = 0; j < 4; ++j) {
                const int oi = (wn << 6) + (j << 4) + ln;
                const int sb = oi & 15;
#pragma unroll
                for (int q = 0; q < 4; ++q) {
                    const int mi = (wm << 6) + (i << 4) + (g << 2) + q;
                    sm[(oi << 7) + ((((mi >> 3) ^ sb)) << 3) + (mi & 7)] =
                        f2b(acc[i][j][q] + bj[j]);
                }
            }
        __syncthreads();
#pragma unroll
        for (int it = 0; it < 8; ++it) {
            const int c = (it << 8) + t;
            const int oi = c >> 4, mi0 = (c & 15) << 3;
            const short8 v = *(const short8*)&sm[(oi << 7) + ((((mi0 >> 3) ^ (oi & 15))) << 3)];
            const int hh = ((o0 >> 6) + (oi >> 6)) & 15;
            const int d = oi & 63;
            const int s0 = (m0 & 1023) + mi0;
            *(short8*)(Vt + (((size_t)((b0 << 4) + hh)) << 16) + (d << 10) + s0) = v;
        }
    } else {
        unsigned short* dst = which ? Kb : Qb;
        const float sc = which ? 1.0f : 0.125f;   // fold 1/sqrt(64) into Q
        // Q/K: LDS row-major tile, elem(mi,oi) = mi*128 + oi
#pragma unroll
        for (int i = 0; i < 4; ++i)
#pragma unroll
            for (int j = 0; j < 4; ++j) {
                const int oi = (wn << 6) + (j << 4) + ln;
#pragma unroll
                for (int q = 0; q < 4; ++q) {
                    const int mi = (wm << 6) + (i << 4) + (g << 2) + q;
                    sm[(mi << 7) + oi] = f2b((acc[i][j][q] + bj[j]) * sc);
                }
            }
        __syncthreads();
#pragma unroll
        for (int it = 0; it < 8; ++it) {
            const int c = (it << 8) + t;
            const int mi = c >> 4, oi0 = (c & 15) << 3;
            const short8 v = *(const short8*)&sm[(mi << 7) + oi0];
            const int s = (m0 & 1023) + mi;
            const int hh = ((o0 >> 6) + (oi0 >> 6)) & 15;
            const int d0 = oi0 & 63;
            *(short8*)(dst + (((size_t)((b0 << 4) + hh)) << 16) + (s << 6) + d0) = v;
        }
    }
}

// ---------------- k2: flash attention with rel-pos via band GEMMs (R2-exact) ----------------
// block = 4 waves, (bh, 64 l-rows); wave w owns l-rows [16w,16w+16)
// per 64-key tile: S = QK^T + Uterm + Wterm, U/W pre-sheared into S-layout buffers.
// dt pruning: U needs dt in [w,w+4], W needs dt in [3-w,7-w]  (20 MFMA vs 32).
// LDS elems (u16): K[0,4096) | E[4096,12288) -> V[4096,8192)+P[8192,12288)
//                  U'[12288,19200) rows=(rr+16) in [0,96), stride 72
//                  W'[19200,25600) rows=rr in [0,64), stride 100 (cols ll+16)
// total 25600 elems = 50 KiB -> 3 blocks/CU
__global__ __launch_bounds__(256, 3) void attn_mfma(
    const unsigned short* __restrict__ Qb, const unsigned short* __restrict__ Kb,
    const unsigned short* __restrict__ Vt, const unsigned short* __restrict__ Eb,
    const float* __restrict__ mask, float* __restrict__ outp)
{
    __shared__ __align__(16) unsigned short sm[25600];
    const int t = threadIdx.x, w = t >> 6;
    const int wu = __builtin_amdgcn_readfirstlane(w);   // wave-uniform in SGPR
    const int ln = t & 15, g = (t >> 4) & 3;
    const int bid = blockIdx.x;
    const int swz = ((bid & 7) << 7) | (bid >> 3);      // XCD-bijective (1024%8==0)
    const int bh = swz >> 4;
    const int l0 = (swz & 15) << 6;
    const int b = bh >> 4, h = bh & 15;
    const size_t hb = (size_t)bh << 16;
    const int x0 = (w << 4) + (g << 2);          // thread's base l-row

    // Q fragments direct from global (pre-scaled; read once, L2-hot)
    const int qr = (w << 4) + ln;
    const short8 qa0 = *(const short8*)(Qb + hb + ((size_t)(l0 + qr) << 6) + (g << 3));
    const short8 qa1 = *(const short8*)(Qb + hb + ((size_t)(l0 + qr) << 6) + 32 + (g << 3));

    floatx4 O[4];
    float mr[4], lr[4];
#pragma unroll
    for (int dt = 0; dt < 4; ++dt) O[dt] = (floatx4){0.f, 0.f, 0.f, 0.f};
#pragma unroll
    for (int q = 0; q < 4; ++q) { mr[q] = -1e30f; lr[q] = 0.f; }

    for (int r0 = 0; r0 < SEQ; r0 += 64) {
        __syncthreads();                         // A: prev PV/V reads done
#pragma unroll
        for (int p = 0; p < 2; ++p) {            // stage K
            const int idx = (p << 8) + t;
            const int row = idx >> 3;
            const int c = (idx & 7) ^ (row & 7);
            GLDS16(Kb + hb + ((size_t)(r0 + row) << 6) + (c << 3),
                   (char*)sm + (p << 12) + (w << 10));
        }
        const int j0 = l0 - r0 + 960;            // E band start, in [0,1920]
#pragma unroll
        for (int p = 0; p < 4; ++p) {            // stage E band (128 rows)
            const int idx = (p << 8) + t;
            const int row = idx >> 3;
            const int c = (idx & 7) ^ (row & 7);
            GLDS16(Eb + ((size_t)(j0 + row) << 6) + (c << 3),
                   (char*)sm + 8192 + (p << 12) + (w << 10));
        }
        __syncthreads();                         // B: staging visible
        short8 kf[4][2];
#pragma unroll
        for (int j = 0; j < 4; ++j) {
            const int kr = (j << 4) + ln;
            kf[j][0] = *(const short8*)&sm[TADDR(0, kr, g)];
            kf[j][1] = *(const short8*)&sm[TADDR(0, kr, 4 + g)];
        }
        const int wr = (w << 4) + ln;            // W A-fragment (this wave's K rows)
        const short8 ka0 = *(const short8*)&sm[TADDR(0, wr, g)];
        const short8 ka1 = *(const short8*)&sm[TADDR(0, wr, 4 + g)];

        floatx4 S[4];
#pragma unroll
        for (int j = 0; j < 4; ++j) {
            floatx4 z = (floatx4){0.f, 0.f, 0.f, 0.f};
            z = __builtin_amdgcn_mfma_f32_16x16x32_bf16(qa0, kf[j][0], z, 0, 0, 0);
            S[j] = __builtin_amdgcn_mfma_f32_16x16x32_bf16(qa1, kf[j][1], z, 0, 0, 0);
        }
        // band GEMMs, pruned per wave; outputs written pre-sheared
#pragma unroll
        for (int dt = 0; dt < 8; ++dt) {
            const bool doU = (dt >= wu) && (dt <= wu + 4);
            const bool doW = (dt >= 3 - wu) && (dt <= 7 - wu);
            if (!doU && !doW) continue;
            const int er = (dt << 4) + ln;
            const short8 e0 = *(const short8*)&sm[TADDR(4096, er, g)];
            const short8 e1 = *(const short8*)&sm[TADDR(4096, er, 4 + g)];
            if (doU) {
                floatx4 z = (floatx4){0.f, 0.f, 0.f, 0.f};
                z = __builtin_amdgcn_mfma_f32_16x16x32_bf16(qa0, e0, z, 0, 0, 0);
                const floatx4 U = __builtin_amdgcn_mfma_f32_16x16x32_bf16(qa1, e1, z, 0, 0, 0);
                // cell (rr = ll-br+63, ll), ll = x0+q, br = 16dt+ln; rr+16 in [0,95]
                int a = 12288 + (x0 - (dt << 4) - ln + 79) * 72 + x0;
#pragma unroll
                for (int q = 0; q < 4; ++q) { sm[a] = f2b(U[q]); a += 73; }
            }
            if (doW) {
                floatx4 z2 = (floatx4){0.f, 0.f, 0.f, 0.f};
                z2 = __builtin_amdgcn_mfma_f32_16x16x32_bf16(ka0, e0, z2, 0, 0, 0);
                const floatx4 Wv = __builtin_amdgcn_mfma_f32_16x16x32_bf16(ka1, e1, z2, 0, 0, 0);
                // cell (rW = x0+q, ll+16 = 16dt+ln+x0+q-47), ll+16 in [1,95]
                int a = 19200 + x0 * 101 + (dt << 4) + ln - 47;
#pragma unroll
                for (int q = 0; q < 4; ++q) { sm[a] = f2b(Wv[q] * 0.125f); a += 101; }
            }
        }
        __syncthreads();                         // C: U'/W' visible; E dead
#pragma unroll
        for (int p = 0; p < 2; ++p) {            // stage V (transposed) over dead E
            const int idx = (p << 8) + t;
            const int row = idx >> 3;            // = d
            const int c = (idx & 7) ^ (row & 7);
            GLDS16(Vt + hb + ((size_t)row << 10) + r0 + (c << 3),
                   (char*)sm + 8192 + (p << 12) + (w << 10));
        }
        // assemble scores: vector b64 reads + global mask (L2-hot)
        float Pw[4][4];
#pragma unroll
        for (int j = 0; j < 4; ++j) {
            const int rr = (j << 4) + ln;
            const float mk = mask[(b << 10) + r0 + rr];
            const ushortx4 u4 = *(const ushortx4*)&sm[12288 + (rr + 16) * 72 + x0];
            const ushortx4 w4 = *(const ushortx4*)&sm[19200 + rr * 100 + 16 + x0];
#pragma unroll
            for (int q = 0; q < 4; ++q)
                S[j][q] += b2f(u4[q]) + b2f(w4[q]) + mk;
        }
#pragma unroll
        for (int q = 0; q < 4; ++q) {
            float tm = fmaxf(fmaxf(S[0][q], S[1][q]), fmaxf(S[2][q], S[3][q]));
            tm = fmaxf(tm, __shfl_xor(tm, 1));
            tm = fmaxf(tm, __shfl_xor(tm, 2));
            tm = fmaxf(tm, __shfl_xor(tm, 4));
            tm = fmaxf(tm, __shfl_xor(tm, 8));
            const float mnew = fmaxf(mr[q], tm);
            const float al = __expf(mr[q] - mnew);
            float sum = 0.f;
#pragma unroll
            for (int j = 0; j < 4; ++j) {
                const float p = __expf(S[j][q] - mnew);
                Pw[j][q] = p; sum += p;
            }
            sum += __shfl_xor(sum, 1);
            sum += __shfl_xor(sum, 2);
            sum += __shfl_xor(sum, 4);
            sum += __shfl_xor(sum, 8);
            lr[q] = lr[q] * al + sum;
            mr[q] = mnew;
#pragma unroll
            for (int dt = 0; dt < 4; ++dt) O[dt][q] *= al;
        }
        // write P (bf16) into [l][r] swizzled tile at elem 8192
#pragma unroll
        for (int j = 0; j < 4; ++j) {
            const int rr = (j << 4) + ln;
#pragma unroll
            for (int q = 0; q < 4; ++q) {
                const int l = x0 + q;
                sm[8192 + (l << 6) + ((((rr >> 3) ^ (l & 7)) << 3)) + (rr & 7)] = f2b(Pw[j][q]);
            }
        }
        __syncthreads();                         // D: P + V visible
        const int pr = (w << 4) + ln;
        const short8 pa0 = *(const short8*)&sm[TADDR(8192, pr, g)];
        const short8 pa1 = *(const short8*)&sm[TADDR(8192, pr, 4 + g)];
#pragma unroll
        for (int dt = 0; dt < 4; ++dt) {
            const int vr = (dt << 4) + ln;       // = d row of V^T tile
            const short8 v0 = *(const short8*)&sm[TADDR(4096, vr, g)];
            const short8 v1 = *(const short8*)&sm[TADDR(4096, vr, 4 + g)];
            O[dt] = __builtin_amdgcn_mfma_f32_16x16x32_bf16(pa0, v0, O[dt], 0, 0, 0);
            O[dt] = __builtin_amdgcn_mfma_f32_16x16x32_bf16(pa1, v1, O[dt], 0, 0, 0);
        }
    }
    // normalize + write out[b, l0+l, h*64 + d]
#pragma unroll
    for (int dt = 0; dt < 4; ++dt)
#pragma unroll
        for (int q = 0; q < 4; ++q) {
            const int l = x0 + q;
            outp[((size_t)b << 20) + ((size_t)(l0 + l) << 10) + (h << 6) + (dt << 4) + ln]
                = O[dt][q] / lr[q];
        }
}

extern "C" void kernel_launch(void* const* d_in, const int* in_sizes, int n_in,
                              void* d_out, int out_size, void* d_ws, size_t ws_size,
                              hipStream_t stream)
{
    const float* hs   = (const float*)d_in[0];   // [4,1024,1024]
    const float* qkvw = (const float*)d_in[1];   // [3072,1024]
    const float* qkvb = (const float*)d_in[2];   // [3072]
    const float* demb = (const float*)d_in[3];   // [2047,64]
    const float* mask = (const float*)d_in[4];   // [4,1,1,1024]
    float* out = (float*)d_out;

    char* ws = (char*)d_ws;
    unsigned short* hsb = (unsigned short*)(ws);              // 8,388,608 B
    unsigned short* Wb  = (unsigned short*)(ws + 8388608);    // 6,291,456 B
    unsigned short* Eb  = (unsigned short*)(ws + 14680064);   //   262,016 B
    unsigned short* Qb  = (unsigned short*)(ws + 14942208);   // 8,388,608 B (pre-scaled)
    unsigned short* Kb  = (unsigned short*)(ws + 23330816);   // 8,388,608 B
    unsigned short* Vt  = (unsigned short*)(ws + 31719424);   // 8,388,608 B (transposed)

    cast_kernel<<<2048, 256, 0, stream>>>(hs, qkvw, demb, hsb, Wb, Eb);
    qkv_gemm<<<dim3(24, 32), 256, 0, stream>>>(hsb, Wb, qkvb, Qb, Kb, Vt);
    attn_mfma<<<1024, 256, 0, stream>>>(Qb, Kb, Vt, Eb, mask, out);
}

// Round 11
// 226.769 us; speedup vs baseline: 3.8600x; 1.0132x over previous
//
#include <hip/hip_runtime.h>
#include <hip/hip_bf16.h>

#define SEQ 1024
#define NH  16

typedef __attribute__((ext_vector_type(8))) short short8;
typedef __attribute__((ext_vector_type(4))) float floatx4;
typedef __attribute__((ext_vector_type(4))) unsigned short ushortx4;

// async global->LDS, 16B per lane; LDS dest = wave-uniform base + lane*16
#define GLDS16(gp, lp) __builtin_amdgcn_global_load_lds( \
    (const __attribute__((address_space(1))) void*)(gp), \
    (__attribute__((address_space(3))) void*)(lp), 16, 0, 0)

// fp32 -> bf16 RNE via native HW convert (compiler pairs into v_cvt_pk_bf16_f32)
__device__ __forceinline__ unsigned short f2b(float f) {
    union { __hip_bfloat16 h; unsigned short u; } v;
    v.h = __float2bfloat16(f);
    return v.u;
}
__device__ __forceinline__ float b2f(unsigned short h) {
    union { unsigned u; float f; } v; v.u = ((unsigned)h) << 16;
    return v.f;
}

// swizzled addr helper (element offsets in a 64-wide bf16 tile: 8 chunks of 16B/row)
#define TADDR(base, row, ch) ((base) + ((row) << 6) + ((((ch) ^ ((row) & 7))) << 3))

// ---------------- k0: fp32 -> bf16 casts ----------------
__global__ void cast_kernel(const float* __restrict__ hs, const float* __restrict__ W,
                            const float* __restrict__ E,
                            unsigned short* __restrict__ hsb,
                            unsigned short* __restrict__ Wb,
                            unsigned short* __restrict__ Eb)
{
    const int QH = 1048576, QW = 786432, QE = 32752;   // quads
    const int NT = QH + QW + QE;
    for (int q = blockIdx.x * 256 + threadIdx.x; q < NT; q += gridDim.x * 256) {
        const float* src; unsigned short* dst; int off;
        if (q < QH)           { src = hs; dst = hsb; off = q; }
        else if (q < QH + QW) { src = W;  dst = Wb;  off = q - QH; }
        else                  { src = E;  dst = Eb;  off = q - QH - QW; }
        const float4 v = *(const float4*)(src + (size_t)off * 4);
        ushortx4 o; o[0] = f2b(v.x); o[1] = f2b(v.y); o[2] = f2b(v.z); o[3] = f2b(v.w);
        *(ushortx4*)(dst + (size_t)off * 4) = o;
    }
}

// ---------------- k1: QKV projection — 2-phase K-loop + LDS-staged coalesced epilogue ----
__global__ __launch_bounds__(256, 3) void qkv_gemm(
    const unsigned short* __restrict__ Ab, const unsigned short* __restrict__ Bb,
    const float* __restrict__ bias,
    unsigned short* __restrict__ Qb, unsigned short* __restrict__ Kb,
    unsigned short* __restrict__ Vt)
{
    __shared__ unsigned short sm[16384];
    const int t = threadIdx.x, w = t >> 6;
    const int ln = t & 15, g = (t >> 4) & 3;
    const int wm = w >> 1, wn = w & 1;
    // XCD-chunked swizzle: 768 wgs = 8 XCDs x 96
    const int bid = blockIdx.x + blockIdx.y * 24;
    const int swzid = (bid & 7) * 96 + (bid >> 3);
    const int m0 = (swzid / 24) << 7, o0 = (swzid % 24) << 7;

    floatx4 acc[4][4];
#pragma unroll
    for (int i = 0; i < 4; ++i)
#pragma unroll
        for (int j = 0; j < 4; ++j) acc[i][j] = (floatx4){0.f, 0.f, 0.f, 0.f};

    auto stage = [&](int kb, int buf) {
        const int base = buf << 14;              // bytes
#pragma unroll
        for (int p = 0; p < 2; ++p) {
            const int idx = (p << 8) + t;
            const int row = idx >> 2;
            const int c = (idx & 3) ^ ((row ^ (row >> 2)) & 3);
            GLDS16(Ab + (size_t)(m0 + row) * 1024 + kb + (c << 3),
                   (char*)sm + base + (p << 12) + (w << 10));
            GLDS16(Bb + (size_t)(o0 + row) * 1024 + kb + (c << 3),
                   (char*)sm + base + 8192 + (p << 12) + (w << 10));
        }
    };

    stage(0, 0);
    __syncthreads();
    int buf = 0;
    for (int kb = 0; kb < 1024; kb += 32) {
        if (kb + 32 < 1024) stage(kb + 32, buf ^ 1);   // issue next-tile loads early
        const int be = buf << 13;                      // elems
        short8 af[4], bf_[4];
#pragma unroll
        for (int i = 0; i < 4; ++i) {
            const int r = (wm << 6) + (i << 4) + ln;
            af[i] = *(const short8*)&sm[be + (r << 5) + ((g ^ ((r ^ (r >> 2)) & 3)) << 3)];
        }
#pragma unroll
        for (int j = 0; j < 4; ++j) {
            const int r = (wn << 6) + (j << 4) + ln;
            bf_[j] = *(const short8*)&sm[be + 4096 + (r << 5) + ((g ^ ((r ^ (r >> 2)) & 3)) << 3)];
        }
#pragma unroll
        for (int i = 0; i < 4; ++i)
#pragma unroll
            for (int j = 0; j < 4; ++j)
                acc[i][j] = __builtin_amdgcn_mfma_f32_16x16x32_bf16(af[i], bf_[j], acc[i][j], 0, 0, 0);
        __syncthreads();                               // drains GLDS + syncs reads
        buf ^= 1;
    }
    // (last barrier above: all staging reads done -> sm reusable for C-tile)

    const int which = o0 >> 10;     // 0=Q 1=K 2=V (block-uniform)
    float bj[4];
#pragma unroll
    for (int j = 0; j < 4; ++j) bj[j] = bias[o0 + (wn << 6) + (j << 4) + ln];
    const int b0 = m0 >> 10;        // tile stays within one batch (128 | 1024)

    if (which == 2) {
        // V: LDS transposed tile, elem(oi,mi) = oi*128 + ((mi>>3)^(oi&15))*8 + (mi&7)
#pragma unroll
        for (int i = 0; i < 4; ++i)
#pragma unroll
            for (int j = 0; j < 4; ++j) {
                const int oi = (wn << 6) + (j << 4) + ln;
                const int sb = oi & 15;
#pragma unroll
                for (int q = 0; q < 4; ++q) {
                    const int mi = (wm << 6) + (i << 4) + (g << 2) + q;
                    sm[(oi << 7) + ((((mi >> 3) ^ sb)) << 3) + (mi & 7)] =
                        f2b(acc[i][j][q] + bj[j]);
                }
            }
        __syncthreads();
#pragma unroll
        for (int it = 0; it < 8; ++it) {
            const int c = (it << 8) + t;
            const int oi = c >> 4, mi0 = (c & 15) << 3;
            const short8 v = *(const short8*)&sm[(oi << 7) + ((((mi0 >> 3) ^ (oi & 15))) << 3)];
            const int hh = ((o0 >> 6) + (oi >> 6)) & 15;
            const int d = oi & 63;
            const int s0 = (m0 & 1023) + mi0;
            *(short8*)(Vt + (((size_t)((b0 << 4) + hh)) << 16) + (d << 10) + s0) = v;
        }
    } else {
        unsigned short* dst = which ? Kb : Qb;
        const float sc = which ? 1.0f : 0.125f;   // fold 1/sqrt(64) into Q
        // Q/K: LDS row-major tile, elem(mi,oi) = mi*128 + oi
#pragma unroll
        for (int i = 0; i < 4; ++i)
#pragma unroll
            for (int j = 0; j < 4; ++j) {
                const int oi = (wn << 6) + (j << 4) + ln;
#pragma unroll
                for (int q = 0; q < 4; ++q) {
                    const int mi = (wm << 6) + (i << 4) + (g << 2) + q;
                    sm[(mi << 7) + oi] = f2b((acc[i][j][q] + bj[j]) * sc);
                }
            }
        __syncthreads();
#pragma unroll
        for (int it = 0; it < 8; ++it) {
            const int c = (it << 8) + t;
            const int mi = c >> 4, oi0 = (c & 15) << 3;
            const short8 v = *(const short8*)&sm[(mi << 7) + oi0];
            const int s = (m0 & 1023) + mi;
            const int hh = ((o0 >> 6) + (oi0 >> 6)) & 15;
            const int d0 = oi0 & 63;
            *(short8*)(dst + (((size_t)((b0 << 4) + hh)) << 16) + (s << 6) + d0) = v;
        }
    }
}

// ---------------- k2: flash attention with rel-pos via band GEMMs (R2-exact structure) ----------------
// block = 4 waves, (bh, 64 l-rows); wave w owns l-rows [16w,16w+16)
// per 64-key tile: S = QK^T + Uterm + Wterm, U/W pre-sheared into S-layout buffers.
// dt pruning: U needs dt in [w,w+4], W needs dt in [3-w,7-w]  (20 MFMA vs 32).
// LDS elems (u16): K[0,4096) | E[4096,12288) -> V[4096,8192)+P[8192,12288)
//                  U'[12288,19200) rows=(rr+16) in [0,96), stride 72
//                  W'[19200,25600) rows=rr in [0,64), stride 100 (cols ll+16)
// total 25600 elems = 50 KiB -> 3 blocks/CU
__global__ __launch_bounds__(256, 3) void attn_mfma(
    const unsigned short* __restrict__ Qb, const unsigned short* __restrict__ Kb,
    const unsigned short* __restrict__ Vt, const unsigned short* __restrict__ Eb,
    const float* __restrict__ mask, float* __restrict__ outp)
{
    __shared__ __align__(16) unsigned short sm[25600];
    const int t = threadIdx.x, w = t >> 6;
    const int wu = __builtin_amdgcn_readfirstlane(w);   // wave-uniform in SGPR
    const int ln = t & 15, g = (t >> 4) & 3;
    const int bid = blockIdx.x;
    const int swz = ((bid & 7) << 7) | (bid >> 3);      // XCD-bijective (1024%8==0)
    const int bh = swz >> 4;
    const int l0 = (swz & 15) << 6;
    const int b = bh >> 4, h = bh & 15;
    const size_t hb = (size_t)bh << 16;
    const int x0 = (w << 4) + (g << 2);          // thread's base l-row

    // Q fragments direct from global (pre-scaled; read once, L2-hot)
    const int qr = (w << 4) + ln;
    const short8 qa0 = *(const short8*)(Qb + hb + ((size_t)(l0 + qr) << 6) + (g << 3));
    const short8 qa1 = *(const short8*)(Qb + hb + ((size_t)(l0 + qr) << 6) + 32 + (g << 3));

    floatx4 O[4];
    float mr[4], lr[4];
#pragma unroll
    for (int dt = 0; dt < 4; ++dt) O[dt] = (floatx4){0.f, 0.f, 0.f, 0.f};
#pragma unroll
    for (int q = 0; q < 4; ++q) { mr[q] = -1e30f; lr[q] = 0.f; }

    for (int r0 = 0; r0 < SEQ; r0 += 64) {
        __syncthreads();                         // A: prev PV/V reads done
#pragma unroll
        for (int p = 0; p < 2; ++p) {            // stage K
            const int idx = (p << 8) + t;
            const int row = idx >> 3;
            const int c = (idx & 7) ^ (row & 7);
            GLDS16(Kb + hb + ((size_t)(r0 + row) << 6) + (c << 3),
                   (char*)sm + (p << 12) + (w << 10));
        }
        const int j0 = l0 - r0 + 960;            // E band start, in [0,1920]
#pragma unroll
        for (int p = 0; p < 4; ++p) {            // stage E band (128 rows)
            const int idx = (p << 8) + t;
            const int row = idx >> 3;
            const int c = (idx & 7) ^ (row & 7);
            GLDS16(Eb + ((size_t)(j0 + row) << 6) + (c << 3),
                   (char*)sm + 8192 + (p << 12) + (w << 10));
        }
        __syncthreads();                         // B: staging visible
        short8 kf[4][2];
#pragma unroll
        for (int j = 0; j < 4; ++j) {
            const int kr = (j << 4) + ln;
            kf[j][0] = *(const short8*)&sm[TADDR(0, kr, g)];
            kf[j][1] = *(const short8*)&sm[TADDR(0, kr, 4 + g)];
        }
        const int wr = (w << 4) + ln;            // W A-fragment (this wave's K rows)
        const short8 ka0 = *(const short8*)&sm[TADDR(0, wr, g)];
        const short8 ka1 = *(const short8*)&sm[TADDR(0, wr, 4 + g)];

        floatx4 S[4];
#pragma unroll
        for (int j = 0; j < 4; ++j) {
            floatx4 z = (floatx4){0.f, 0.f, 0.f, 0.f};
            z = __builtin_amdgcn_mfma_f32_16x16x32_bf16(qa0, kf[j][0], z, 0, 0, 0);
            S[j] = __builtin_amdgcn_mfma_f32_16x16x32_bf16(qa1, kf[j][1], z, 0, 0, 0);
        }
        // band GEMMs, pruned per wave; outputs written pre-sheared
#pragma unroll
        for (int dt = 0; dt < 8; ++dt) {
            const bool doU = (dt >= wu) && (dt <= wu + 4);
            const bool doW = (dt >= 3 - wu) && (dt <= 7 - wu);
            if (!doU && !doW) continue;
            const int er = (dt << 4) + ln;
            const short8 e0 = *(const short8*)&sm[TADDR(4096, er, g)];
            const short8 e1 = *(const short8*)&sm[TADDR(4096, er, 4 + g)];
            if (doU) {
                floatx4 z = (floatx4){0.f, 0.f, 0.f, 0.f};
                z = __builtin_amdgcn_mfma_f32_16x16x32_bf16(qa0, e0, z, 0, 0, 0);
                const floatx4 U = __builtin_amdgcn_mfma_f32_16x16x32_bf16(qa1, e1, z, 0, 0, 0);
                // cell (rr = ll-br+63, ll), ll = x0+q, br = 16dt+ln; rr+16 in [0,95]
                int a = 12288 + (x0 - (dt << 4) - ln + 79) * 72 + x0;
#pragma unroll
                for (int q = 0; q < 4; ++q) { sm[a] = f2b(U[q]); a += 73; }
            }
            if (doW) {
                floatx4 z2 = (floatx4){0.f, 0.f, 0.f, 0.f};
                z2 = __builtin_amdgcn_mfma_f32_16x16x32_bf16(ka0, e0, z2, 0, 0, 0);
                const floatx4 Wv = __builtin_amdgcn_mfma_f32_16x16x32_bf16(ka1, e1, z2, 0, 0, 0);
                // cell (rW = x0+q, ll+16 = 16dt+ln+x0+q-47), ll+16 in [1,95]
                int a = 19200 + x0 * 101 + (dt << 4) + ln - 47;
#pragma unroll
                for (int q = 0; q < 4; ++q) { sm[a] = f2b(Wv[q] * 0.125f); a += 101; }
            }
        }
        __syncthreads();                         // C: U'/W' visible; E dead
#pragma unroll
        for (int p = 0; p < 2; ++p) {            // stage V (transposed) over dead E
            const int idx = (p << 8) + t;
            const int row = idx >> 3;            // = d
            const int c = (idx & 7) ^ (row & 7);
            GLDS16(Vt + hb + ((size_t)row << 10) + r0 + (c << 3),
                   (char*)sm + 8192 + (p << 12) + (w << 10));
        }
        // assemble scores: vector b64 reads + global mask (L2-hot)
        float Pw[4][4];
#pragma unroll
        for (int j = 0; j < 4; ++j) {
            const int rr = (j << 4) + ln;
            const float mk = mask[(b << 10) + r0 + rr];
            const ushortx4 u4 = *(const ushortx4*)&sm[12288 + (rr + 16) * 72 + x0];
            const ushortx4 w4 = *(const ushortx4*)&sm[19200 + rr * 100 + 16 + x0];
#pragma unroll
            for (int q = 0; q < 4; ++q)
                S[j][q] += b2f(u4[q]) + b2f(w4[q]) + mk;
        }
#pragma unroll
        for (int q = 0; q < 4; ++q) {
            float tm = fmaxf(fmaxf(S[0][q], S[1][q]), fmaxf(S[2][q], S[3][q]));
            tm = fmaxf(tm, __shfl_xor(tm, 1));
            tm = fmaxf(tm, __shfl_xor(tm, 2));
            tm = fmaxf(tm, __shfl_xor(tm, 4));
            tm = fmaxf(tm, __shfl_xor(tm, 8));
            const float mnew = fmaxf(mr[q], tm);
            const float al = __expf(mr[q] - mnew);
            float sum = 0.f;
#pragma unroll
            for (int j = 0; j < 4; ++j) {
                const float p = __expf(S[j][q] - mnew);
                Pw[j][q] = p; sum += p;
            }
            sum += __shfl_xor(sum, 1);
            sum += __shfl_xor(sum, 2);
            sum += __shfl_xor(sum, 4);
            sum += __shfl_xor(sum, 8);
            lr[q] = lr[q] * al + sum;
            mr[q] = mnew;
#pragma unroll
            for (int dt = 0; dt < 4; ++dt) O[dt][q] *= al;
        }
        // write P (bf16) into [l][r] swizzled tile at elem 8192
#pragma unroll
        for (int j = 0; j < 4; ++j) {
            const int rr = (j << 4) + ln;
#pragma unroll
            for (int q = 0; q < 4; ++q) {
                const int l = x0 + q;
                sm[8192 + (l << 6) + ((((rr >> 3) ^ (l & 7)) << 3)) + (rr & 7)] = f2b(Pw[j][q]);
            }
        }
        __syncthreads();                         // D: P + V visible
        const int pr = (w << 4) + ln;
        const short8 pa0 = *(const short8*)&sm[TADDR(8192, pr, g)];
        const short8 pa1 = *(const short8*)&sm[TADDR(8192, pr, 4 + g)];
#pragma unroll
        for (int dt = 0; dt < 4; ++dt) {
            const int vr = (dt << 4) + ln;       // = d row of V^T tile
            const short8 v0 = *(const short8*)&sm[TADDR(4096, vr, g)];
            const short8 v1 = *(const short8*)&sm[TADDR(4096, vr, 4 + g)];
            O[dt] = __builtin_amdgcn_mfma_f32_16x16x32_bf16(pa0, v0, O[dt], 0, 0, 0);
            O[dt] = __builtin_amdgcn_mfma_f32_16x16x32_bf16(pa1, v1, O[dt], 0, 0, 0);
        }
    }
    // normalize + write out[b, l0+l, h*64 + d]
#pragma unroll
    for (int dt = 0; dt < 4; ++dt)
#pragma unroll
        for (int q = 0; q < 4; ++q) {
            const int l = x0 + q;
            outp[((size_t)b << 20) + ((size_t)(l0 + l) << 10) + (h << 6) + (dt << 4) + ln]
                = O[dt][q] / lr[q];
        }
}

extern "C" void kernel_launch(void* const* d_in, const int* in_sizes, int n_in,
                              void* d_out, int out_size, void* d_ws, size_t ws_size,
                              hipStream_t stream)
{
    const float* hs   = (const float*)d_in[0];   // [4,1024,1024]
    const float* qkvw = (const float*)d_in[1];   // [3072,1024]
    const float* qkvb = (const float*)d_in[2];   // [3072]
    const float* demb = (const float*)d_in[3];   // [2047,64]
    const float* mask = (const float*)d_in[4];   // [4,1,1,1024]
    float* out = (float*)d_out;

    char* ws = (char*)d_ws;
    unsigned short* hsb = (unsigned short*)(ws);              // 8,388,608 B
    unsigned short* Wb  = (unsigned short*)(ws + 8388608);    // 6,291,456 B
    unsigned short* Eb  = (unsigned short*)(ws + 14680064);   //   262,016 B
    unsigned short* Qb  = (unsigned short*)(ws + 14942208);   // 8,388,608 B (pre-scaled)
    unsigned short* Kb  = (unsigned short*)(ws + 23330816);   // 8,388,608 B
    unsigned short* Vt  = (unsigned short*)(ws + 31719424);   // 8,388,608 B (transposed)

    cast_kernel<<<2048, 256, 0, stream>>>(hs, qkvw, demb, hsb, Wb, Eb);
    qkv_gemm<<<dim3(24, 32), 256, 0, stream>>>(hsb, Wb, qkvb, Qb, Kb, Vt);
    attn_mfma<<<1024, 256, 0, stream>>>(Qb, Kb, Vt, Eb, mask, out);
}